// Round 7
// baseline (637.122 us; speedup 1.0000x reference)
//
#include <hip/hip_runtime.h>
#include <hip/hip_bf16.h>
#include <math.h>

#define HID 64
#define KT 64

static inline size_t align256(size_t x) { return (x + 255) & ~(size_t)255; }

__device__ inline void gld_lds16(const float* g, float* lds) {
  __builtin_amdgcn_global_load_lds((const __attribute__((address_space(1))) void*)g,
                                   (__attribute__((address_space(3))) void*)lds, 16, 0, 0);
}

// ---------- graph preprocessing ----------

__global__ void count_dst_kernel(const int* __restrict__ dst, int* __restrict__ cnt, int E) {
  int e = blockIdx.x * blockDim.x + threadIdx.x;
  if (e < E) atomicAdd(&cnt[dst[e]], 1);
}

__global__ void dinv_kernel(const int* __restrict__ cnt, float* __restrict__ dinv, int N) {
  int i = blockIdx.x * blockDim.x + threadIdx.x;
  if (i < N) dinv[i] = rsqrtf((float)(cnt[i] + 1));  // +1 self-loop; deg >= 1 always
}

// ---------- 3-phase hierarchical exclusive scan (cnt -> rowptr, cursor) ----------

__global__ __launch_bounds__(1024) void scan_local_kernel(const int* __restrict__ cnt,
                                                          int* __restrict__ rowptr,
                                                          int* __restrict__ bsum, int N) {
  __shared__ int sh[1024];
  int t = threadIdx.x;
  int i = blockIdx.x * 1024 + t;
  int v = (i < N) ? cnt[i] : 0;
  sh[t] = v;
  __syncthreads();
  for (int off = 1; off < 1024; off <<= 1) {
    int u = (t >= off) ? sh[t - off] : 0;
    __syncthreads();
    sh[t] += u;
    __syncthreads();
  }
  if (i < N) rowptr[i] = sh[t] - v;  // local exclusive
  if (t == 1023) bsum[blockIdx.x] = sh[t];
}

__global__ __launch_bounds__(1024) void scan_bsum_kernel(const int* __restrict__ bsum,
                                                         int* __restrict__ boff,
                                                         int* __restrict__ rowptr_last, int B) {
  __shared__ int sh[1024];
  int t = threadIdx.x;
  int v = (t < B) ? bsum[t] : 0;
  sh[t] = v;
  __syncthreads();
  for (int off = 1; off < 1024; off <<= 1) {
    int u = (t >= off) ? sh[t - off] : 0;
    __syncthreads();
    sh[t] += u;
    __syncthreads();
  }
  if (t < B) boff[t] = sh[t] - v;
  if (t == 1023) *rowptr_last = sh[t];
}

__global__ void scan_add_kernel(const int* __restrict__ boff, int* __restrict__ rowptr,
                                int* __restrict__ cursor, int N) {
  int i = blockIdx.x * blockDim.x + threadIdx.x;
  if (i >= N) return;
  int r = rowptr[i] + boff[i >> 10];
  rowptr[i] = r;
  cursor[i] = r;
}

// ---------- two-phase binned scatter (kills write amplification) ----------
// Phase A: append edges to NB bucket streams (bucket = dst>>5); streams are
// sequential so 64 B lines fill completely. Phase B: coalesced read of staged,
// fine scatter within each bucket's ~4 KB epack window (localized writes).

__global__ void bcur_init_kernel(const int* __restrict__ rowptr, int* __restrict__ bcur, int NB) {
  int b = blockIdx.x * blockDim.x + threadIdx.x;
  if (b < NB) bcur[b] = rowptr[b << 5];
}

__global__ void bin_kernel(const int* __restrict__ src, const int* __restrict__ dst,
                           const float* __restrict__ dinv, int* __restrict__ bcur,
                           int4* __restrict__ staged, int E) {
  int e = blockIdx.x * blockDim.x + threadIdx.x;
  if (e >= E) return;
  int s = src[e], d = dst[e];
  int pos = atomicAdd(&bcur[d >> 5], 1);
  staged[pos] = make_int4(s, d, __float_as_int(dinv[s] * dinv[d]), 0);
}

__global__ void finesort_kernel(const int4* __restrict__ staged, int* __restrict__ cursor,
                                int2* __restrict__ epack, int E) {
  int j = blockIdx.x * blockDim.x + threadIdx.x;
  if (j >= E) return;
  int4 t = staged[j];
  int pos = atomicAdd(&cursor[t.y], 1);
  epack[pos] = make_int2(t.x, t.z);
}

// ---------- GEMM: out[N,64] = x[N,K] @ W[K,64] (bias fused into agg) ----------
// Block = 64 rows; x/W staged via global_load_lds_dwordx4. 4x4 micro-tile:
// lane = (rg=lane>>4 -> rows w*16+rg*4+{0..3}, cg=lane&15 -> cols cg*4+{0..3}).
// Xs k-groups XOR-swizzled by (row>>2)&3 on the GLOBAL side of the staging DMA
// (LDS side must stay lane-contiguous) -> conflict-free x reads.

template <int K, typename OT>
__global__ __launch_bounds__(256, 4) void gemm_kernel(const float* __restrict__ x,
                                                      const float* __restrict__ W,
                                                      OT* __restrict__ out, int N) {
  __shared__ float Xs[64 * KT];  // [row][swizzled k-group]
  __shared__ float Ws[KT * 64];  // [kk][col]
  const int t = threadIdx.x;
  const int lane = t & 63;
  const int w = t >> 6;
  const int rg = lane >> 4;
  const int cg = lane & 15;
  const int row0 = blockIdx.x * 64;
  float4 acc[4];
#pragma unroll
  for (int r = 0; r < 4; ++r) acc[r] = make_float4(0.f, 0.f, 0.f, 0.f);

  for (int k0 = 0; k0 < K; k0 += KT) {
    if (k0) __syncthreads();
    const float* Wg = W + (size_t)k0 * HID;
#pragma unroll
    for (int c = 0; c < 4; ++c) {
      int idx = c * 256 + t;  // float4 slot in 4096-float tile
      gld_lds16(Wg + idx * 4, &Ws[idx * 4]);
      int srow = idx >> 4;                         // LDS row for this slot
      int sg = (idx & 15) ^ ((srow >> 2) & 3);     // swizzled source k-group
      int grow = min(row0 + srow, N - 1);
      gld_lds16(x + (size_t)grow * K + k0 + (sg << 2), &Xs[idx * 4]);
    }
    __syncthreads();
    const int rbase = w * 16 + rg * 4;
#pragma unroll 4
    for (int kb = 0; kb < KT / 4; ++kb) {
      float4 wq0 = *(const float4*)&Ws[(4 * kb + 0) * HID + cg * 4];
      float4 wq1 = *(const float4*)&Ws[(4 * kb + 1) * HID + cg * 4];
      float4 wq2 = *(const float4*)&Ws[(4 * kb + 2) * HID + cg * 4];
      float4 wq3 = *(const float4*)&Ws[(4 * kb + 3) * HID + cg * 4];
      const int sg = (kb ^ rg) << 2;  // (row>>2)&3 == rg for rows rbase..rbase+3
#pragma unroll
      for (int r = 0; r < 4; ++r) {
        float4 xv = *(const float4*)&Xs[(rbase + r) * KT + sg];
        acc[r].x = fmaf(xv.w, wq3.x, fmaf(xv.z, wq2.x, fmaf(xv.y, wq1.x, fmaf(xv.x, wq0.x, acc[r].x))));
        acc[r].y = fmaf(xv.w, wq3.y, fmaf(xv.z, wq2.y, fmaf(xv.y, wq1.y, fmaf(xv.x, wq0.y, acc[r].y))));
        acc[r].z = fmaf(xv.w, wq3.z, fmaf(xv.z, wq2.z, fmaf(xv.y, wq1.z, fmaf(xv.x, wq0.z, acc[r].z))));
        acc[r].w = fmaf(xv.w, wq3.w, fmaf(xv.z, wq2.w, fmaf(xv.y, wq1.w, fmaf(xv.x, wq0.w, acc[r].w))));
      }
    }
  }
#pragma unroll
  for (int r = 0; r < 4; ++r) {
    int row = row0 + w * 16 + rg * 4 + r;
    if (row < N) {
      OT* o = out + (size_t)row * HID + cg * 4;
      o[0] = (OT)acc[r].x; o[1] = (OT)acc[r].y; o[2] = (OT)acc[r].z; o[3] = (OT)acc[r].w;
    }
  }
}

// ---------- fused aggregation (bf16 gather, 2 features/lane, 2 nodes/wave) ----------
// out[d] = sum_{e:dst=d} norm_e*h[src_e] + dinv[d]^2*h[d] + b  (+relu+L2norm)

__device__ inline float bf_lo(unsigned int u) { return __uint_as_float(u << 16); }
__device__ inline float bf_hi(unsigned int u) { return __uint_as_float(u & 0xffff0000u); }

template <bool RELU_NORM>
__global__ void agg_kernel(const int* __restrict__ rowptr, const int2* __restrict__ epack,
                           const float* __restrict__ dinv, const unsigned int* __restrict__ h32,
                           const float* __restrict__ bias, float* __restrict__ out, int N) {
  int pair = (blockIdx.x * blockDim.x + threadIdx.x) >> 6;
  int lane = threadIdx.x & 63;
  int node = pair * 2 + (lane >> 5);
  if (node >= N) return;
  int sub = lane & 31;  // features sub*2, sub*2+1
  int beg = rowptr[node];
  int end = rowptr[node + 1];
  float di = dinv[node];
  unsigned int su = h32[(size_t)node * 32 + sub];
  float acc0 = di * di * bf_lo(su) + bias[sub * 2];
  float acc1 = di * di * bf_hi(su) + bias[sub * 2 + 1];
  int j = beg;
  for (; j + 8 <= end; j += 8) {
    int2 e[8];
    unsigned int hv[8];
#pragma unroll
    for (int u = 0; u < 8; ++u) e[u] = epack[j + u];
#pragma unroll
    for (int u = 0; u < 8; ++u) hv[u] = h32[(size_t)e[u].x * 32 + sub];
#pragma unroll
    for (int u = 0; u < 8; ++u) {
      float wn = __int_as_float(e[u].y);
      acc0 = fmaf(wn, bf_lo(hv[u]), acc0);
      acc1 = fmaf(wn, bf_hi(hv[u]), acc1);
    }
  }
  for (; j < end; ++j) {
    int2 e0 = epack[j];
    unsigned int hu = h32[(size_t)e0.x * 32 + sub];
    float wn = __int_as_float(e0.y);
    acc0 = fmaf(wn, bf_lo(hu), acc0);
    acc1 = fmaf(wn, bf_hi(hu), acc1);
  }
  float2* o2 = (float2*)out;
  if (RELU_NORM) {
    float v0 = fmaxf(acc0, 0.f);
    float v1 = fmaxf(acc1, 0.f);
    float ss = v0 * v0 + v1 * v1;
#pragma unroll
    for (int off = 16; off; off >>= 1) ss += __shfl_xor(ss, off, 64);  // within 32-half
    float inv = 1.f / fmaxf(sqrtf(ss), 1e-12f);
    o2[(size_t)node * 32 + sub] = make_float2(v0 * inv, v1 * inv);
  } else {
    o2[(size_t)node * 32 + sub] = make_float2(acc0, acc1);
  }
}

// ---------- atomic fallback path (fp32; only if ws too small for CSR) ----------

__global__ void init_agg_kernel(const float* __restrict__ dinv, const float* __restrict__ h,
                                const float* __restrict__ bias, float* __restrict__ out, int N) {
  int t = blockIdx.x * blockDim.x + threadIdx.x;
  int i = t >> 6, f = t & 63;
  if (i >= N) return;
  float di = dinv[i];
  out[t] = di * di * h[t] + bias[f];
}

__global__ void edge_atomic_kernel(const int* __restrict__ src, const int* __restrict__ dst,
                                   const float* __restrict__ dinv, const float* __restrict__ h,
                                   float* __restrict__ out, int E) {
  int t = blockIdx.x * blockDim.x + threadIdx.x;
  int e = t >> 6;
  if (e >= E) return;
  int f = t & 63;
  int s = src[e], d = dst[e];
  atomicAdd(&out[(size_t)d * HID + f], dinv[s] * dinv[d] * h[(size_t)s * HID + f]);
}

__global__ void relu_norm_kernel(float* __restrict__ hbuf, int N) {
  int t = blockIdx.x * blockDim.x + threadIdx.x;
  int i = t >> 6;
  if (i >= N) return;
  float v = fmaxf(hbuf[t], 0.f);
  float ss = v * v;
#pragma unroll
  for (int off = 32; off; off >>= 1) ss += __shfl_xor(ss, off, 64);
  hbuf[t] = v / fmaxf(sqrtf(ss), 1e-12f);
}

// ---------- host ----------

extern "C" void kernel_launch(void* const* d_in, const int* in_sizes, int n_in,
                              void* d_out, int out_size, void* d_ws, size_t ws_size,
                              hipStream_t stream) {
  const float* x  = (const float*)d_in[0];
  const int*   ei = (const int*)d_in[1];
  const float* W1 = (const float*)d_in[2];
  const float* b1 = (const float*)d_in[3];
  const float* W2 = (const float*)d_in[4];
  const float* b2 = (const float*)d_in[5];
  const float* W3 = (const float*)d_in[6];
  const float* b3 = (const float*)d_in[7];
  float* out = (float*)d_out;

  const int IN = in_sizes[2] / HID;   // 256
  const int N  = in_sizes[0] / IN;    // 100000
  const int E  = in_sizes[1] / 2;     // 1600000
  const int NB = (N + 31) / 32;       // buckets of 32 nodes
  const int* srcI = ei;
  const int* dstI = ei + E;

  char* w = (char*)d_ws;
  size_t off = 0;
  auto alloc = [&](size_t bytes) { void* p = w + off; off = align256(off + bytes); return p; };
  float* A      = (float*)alloc((size_t)N * HID * 4);  // fp32 fallback / bf16 gather buffer
  float* dinv   = (float*)alloc((size_t)N * 4);
  int*   cnt    = (int*)alloc((size_t)N * 4);
  size_t base_need = off;
  int*   rowptr = (int*)alloc((size_t)(N + 1) * 4);
  int*   cursor = (int*)alloc((size_t)N * 4);
  int*   bsum   = (int*)alloc(1024 * 4);
  int*   boff   = (int*)alloc(1024 * 4);
  int*   bcur   = (int*)alloc((size_t)NB * 4);
  int2*  epack  = (int2*)alloc((size_t)E * 8);
  int4*  staged = (int4*)alloc((size_t)E * 16);
  size_t csr_need = off;

  if (base_need > ws_size) return;
  const bool use_csr = (csr_need <= ws_size);
  __hip_bfloat16* Ab = (__hip_bfloat16*)A;
  unsigned int* Ab32 = (unsigned int*)A;

  const int blkE    = (E + 255) / 256;
  const int blkN    = (N + 255) / 256;
  const int blkNB   = (NB + 255) / 256;
  const int blkScan = (N + 1023) / 1024;
  const int blkRow  = (N + 63) / 64;
  const int blkWave = (N * 64 + 255) / 256;
  const int blkAgg  = ((size_t)((N + 1) / 2) * 64 + 255) / 256;  // 2 nodes/wave
  const int blkEF   = ((size_t)E * 64 + 255) / 256;

  hipMemsetAsync(cnt, 0, (size_t)N * 4, stream);
  count_dst_kernel<<<blkE, 256, 0, stream>>>(dstI, cnt, E);
  dinv_kernel<<<blkN, 256, 0, stream>>>(cnt, dinv, N);

  if (use_csr) {
    scan_local_kernel<<<blkScan, 1024, 0, stream>>>(cnt, rowptr, bsum, N);
    scan_bsum_kernel<<<1, 1024, 0, stream>>>(bsum, boff, rowptr + N, blkScan);
    scan_add_kernel<<<blkN, 256, 0, stream>>>(boff, rowptr, cursor, N);
    bcur_init_kernel<<<blkNB, 256, 0, stream>>>(rowptr, bcur, NB);
    bin_kernel<<<blkE, 256, 0, stream>>>(srcI, dstI, dinv, bcur, staged, E);
    finesort_kernel<<<blkE, 256, 0, stream>>>(staged, cursor, epack, E);

    gemm_kernel<256><<<blkRow, 256, 0, stream>>>(x, W1, Ab, N);
    agg_kernel<true><<<blkAgg, 256, 0, stream>>>(rowptr, epack, dinv, Ab32, b1, out, N);
    gemm_kernel<64><<<blkRow, 256, 0, stream>>>(out, W2, Ab, N);
    agg_kernel<true><<<blkAgg, 256, 0, stream>>>(rowptr, epack, dinv, Ab32, b2, out, N);
    gemm_kernel<64><<<blkRow, 256, 0, stream>>>(out, W3, Ab, N);
    agg_kernel<false><<<blkAgg, 256, 0, stream>>>(rowptr, epack, dinv, Ab32, b3, out, N);
  } else {
    gemm_kernel<256><<<blkRow, 256, 0, stream>>>(x, W1, A, N);
    init_agg_kernel<<<blkWave, 256, 0, stream>>>(dinv, A, b1, out, N);
    edge_atomic_kernel<<<blkEF, 256, 0, stream>>>(srcI, dstI, dinv, A, out, E);
    relu_norm_kernel<<<blkWave, 256, 0, stream>>>(out, N);

    gemm_kernel<64><<<blkRow, 256, 0, stream>>>(out, W2, A, N);
    init_agg_kernel<<<blkWave, 256, 0, stream>>>(dinv, A, b2, out, N);
    edge_atomic_kernel<<<blkEF, 256, 0, stream>>>(srcI, dstI, dinv, A, out, E);
    relu_norm_kernel<<<blkWave, 256, 0, stream>>>(out, N);

    gemm_kernel<64><<<blkRow, 256, 0, stream>>>(out, W3, A, N);
    init_agg_kernel<<<blkWave, 256, 0, stream>>>(dinv, A, b3, out, N);
    edge_atomic_kernel<<<blkEF, 256, 0, stream>>>(srcI, dstI, dinv, A, out, E);
  }
}

// Round 8
// 497.607 us; speedup vs baseline: 1.2804x; 1.2804x over previous
//
#include <hip/hip_runtime.h>
#include <hip/hip_bf16.h>
#include <math.h>

#define HID 64
#define KT 64

static inline size_t align256(size_t x) { return (x + 255) & ~(size_t)255; }

__device__ inline void gld_lds16(const float* g, float* lds) {
  __builtin_amdgcn_global_load_lds((const __attribute__((address_space(1))) void*)g,
                                   (__attribute__((address_space(3))) void*)lds, 16, 0, 0);
}

// ---------- graph preprocessing ----------

__global__ void count_dst_kernel(const int* __restrict__ dst, int* __restrict__ cnt, int E) {
  int e = blockIdx.x * blockDim.x + threadIdx.x;
  if (e < E) atomicAdd(&cnt[dst[e]], 1);
}

__global__ void dinv_kernel(const int* __restrict__ cnt, float* __restrict__ dinv, int N) {
  int i = blockIdx.x * blockDim.x + threadIdx.x;
  if (i < N) dinv[i] = rsqrtf((float)(cnt[i] + 1));  // +1 self-loop; deg >= 1 always
}

// ---------- 3-phase hierarchical exclusive scan (cnt -> rowptr, cursor) ----------

__global__ __launch_bounds__(1024) void scan_local_kernel(const int* __restrict__ cnt,
                                                          int* __restrict__ rowptr,
                                                          int* __restrict__ bsum, int N) {
  __shared__ int sh[1024];
  int t = threadIdx.x;
  int i = blockIdx.x * 1024 + t;
  int v = (i < N) ? cnt[i] : 0;
  sh[t] = v;
  __syncthreads();
  for (int off = 1; off < 1024; off <<= 1) {
    int u = (t >= off) ? sh[t - off] : 0;
    __syncthreads();
    sh[t] += u;
    __syncthreads();
  }
  if (i < N) rowptr[i] = sh[t] - v;  // local exclusive
  if (t == 1023) bsum[blockIdx.x] = sh[t];
}

__global__ __launch_bounds__(1024) void scan_bsum_kernel(const int* __restrict__ bsum,
                                                         int* __restrict__ boff,
                                                         int* __restrict__ rowptr_last, int B) {
  __shared__ int sh[1024];
  int t = threadIdx.x;
  int v = (t < B) ? bsum[t] : 0;
  sh[t] = v;
  __syncthreads();
  for (int off = 1; off < 1024; off <<= 1) {
    int u = (t >= off) ? sh[t - off] : 0;
    __syncthreads();
    sh[t] += u;
    __syncthreads();
  }
  if (t < B) boff[t] = sh[t] - v;
  if (t == 1023) *rowptr_last = sh[t];
}

__global__ void scan_add_kernel(const int* __restrict__ boff, int* __restrict__ rowptr,
                                int* __restrict__ cursor, int N) {
  int i = blockIdx.x * blockDim.x + threadIdx.x;
  if (i >= N) return;
  int r = rowptr[i] + boff[i >> 10];
  rowptr[i] = r;
  cursor[i] = r;
}

// single-phase scatter (R6 form — at the random-line-write ceiling; binned
// variants amplify writes identically because per-XCD L2s evict partial lines)
__global__ void scatter_kernel(const int* __restrict__ src, const int* __restrict__ dst,
                               const float* __restrict__ dinv, int* __restrict__ cursor,
                               int2* __restrict__ epack, int E) {
  int e = blockIdx.x * blockDim.x + threadIdx.x;
  if (e >= E) return;
  int s = src[e], d = dst[e];
  int pos = atomicAdd(&cursor[d], 1);
  epack[pos] = make_int2(s, __float_as_int(dinv[s] * dinv[d]));
}

// ---------- GEMM: out[N,64] = x[N,K] @ W[K,64] (bias fused into agg) ----------
// Block = 64 rows; x/W staged via global_load_lds_dwordx4. 4x4 micro-tile;
// Xs k-groups XOR-swizzled on the GLOBAL side of the staging DMA.

template <int K, typename OT>
__global__ __launch_bounds__(256, 4) void gemm_kernel(const float* __restrict__ x,
                                                      const float* __restrict__ W,
                                                      OT* __restrict__ out, int N) {
  __shared__ float Xs[64 * KT];  // [row][swizzled k-group]
  __shared__ float Ws[KT * 64];  // [kk][col]
  const int t = threadIdx.x;
  const int lane = t & 63;
  const int w = t >> 6;
  const int rg = lane >> 4;
  const int cg = lane & 15;
  const int row0 = blockIdx.x * 64;
  float4 acc[4];
#pragma unroll
  for (int r = 0; r < 4; ++r) acc[r] = make_float4(0.f, 0.f, 0.f, 0.f);

  for (int k0 = 0; k0 < K; k0 += KT) {
    if (k0) __syncthreads();
    const float* Wg = W + (size_t)k0 * HID;
#pragma unroll
    for (int c = 0; c < 4; ++c) {
      int idx = c * 256 + t;  // float4 slot in 4096-float tile
      gld_lds16(Wg + idx * 4, &Ws[idx * 4]);
      int srow = idx >> 4;                         // LDS row for this slot
      int sg = (idx & 15) ^ ((srow >> 2) & 3);     // swizzled source k-group
      int grow = min(row0 + srow, N - 1);
      gld_lds16(x + (size_t)grow * K + k0 + (sg << 2), &Xs[idx * 4]);
    }
    __syncthreads();
    const int rbase = w * 16 + rg * 4;
#pragma unroll 4
    for (int kb = 0; kb < KT / 4; ++kb) {
      float4 wq0 = *(const float4*)&Ws[(4 * kb + 0) * HID + cg * 4];
      float4 wq1 = *(const float4*)&Ws[(4 * kb + 1) * HID + cg * 4];
      float4 wq2 = *(const float4*)&Ws[(4 * kb + 2) * HID + cg * 4];
      float4 wq3 = *(const float4*)&Ws[(4 * kb + 3) * HID + cg * 4];
      const int sg = (kb ^ rg) << 2;  // (row>>2)&3 == rg for rows rbase..rbase+3
#pragma unroll
      for (int r = 0; r < 4; ++r) {
        float4 xv = *(const float4*)&Xs[(rbase + r) * KT + sg];
        acc[r].x = fmaf(xv.w, wq3.x, fmaf(xv.z, wq2.x, fmaf(xv.y, wq1.x, fmaf(xv.x, wq0.x, acc[r].x))));
        acc[r].y = fmaf(xv.w, wq3.y, fmaf(xv.z, wq2.y, fmaf(xv.y, wq1.y, fmaf(xv.x, wq0.y, acc[r].y))));
        acc[r].z = fmaf(xv.w, wq3.z, fmaf(xv.z, wq2.z, fmaf(xv.y, wq1.z, fmaf(xv.x, wq0.z, acc[r].z))));
        acc[r].w = fmaf(xv.w, wq3.w, fmaf(xv.z, wq2.w, fmaf(xv.y, wq1.w, fmaf(xv.x, wq0.w, acc[r].w))));
      }
    }
  }
#pragma unroll
  for (int r = 0; r < 4; ++r) {
    int row = row0 + w * 16 + rg * 4 + r;
    if (row < N) {
      OT* o = out + (size_t)row * HID + cg * 4;
      o[0] = (OT)acc[r].x; o[1] = (OT)acc[r].y; o[2] = (OT)acc[r].z; o[3] = (OT)acc[r].w;
    }
  }
}

// ---------- fused aggregation: 4 nodes/wave, 16 lanes/node, 4 feats/lane ----------
// out[d] = sum_{e:dst=d} norm_e*h[src_e] + dinv[d]^2*h[d] + b  (+relu+L2norm)
// One uint2 (4 bf16) gather per lane per edge -> one VMEM instruction serves
// 4 edges (one per 16-lane quarter); 4 independent load chains per wave.

__device__ inline float bf_lo(unsigned int u) { return __uint_as_float(u << 16); }
__device__ inline float bf_hi(unsigned int u) { return __uint_as_float(u & 0xffff0000u); }

template <bool RELU_NORM>
__global__ void agg_kernel(const int* __restrict__ rowptr, const int2* __restrict__ epack,
                           const float* __restrict__ dinv, const uint2* __restrict__ h64,
                           const float* __restrict__ bias, float* __restrict__ out, int N) {
  int grp = (blockIdx.x * blockDim.x + threadIdx.x) >> 6;
  int lane = threadIdx.x & 63;
  int q = lane >> 4;        // quarter 0..3 -> node
  int sub = lane & 15;      // features sub*4 .. sub*4+3
  int node = grp * 4 + q;
  if (node >= N) return;
  int beg = rowptr[node];
  int end = rowptr[node + 1];
  float di = dinv[node];
  float dd = di * di;
  uint2 su = h64[(size_t)node * 16 + sub];
  float4 b4 = *(const float4*)&bias[sub * 4];
  float a0 = dd * bf_lo(su.x) + b4.x;
  float a1 = dd * bf_hi(su.x) + b4.y;
  float a2 = dd * bf_lo(su.y) + b4.z;
  float a3 = dd * bf_hi(su.y) + b4.w;
  int j = beg;
  for (; j + 8 <= end; j += 8) {
    int2 e[8];
    uint2 hv[8];
#pragma unroll
    for (int u = 0; u < 8; ++u) e[u] = epack[j + u];
#pragma unroll
    for (int u = 0; u < 8; ++u) hv[u] = h64[(size_t)e[u].x * 16 + sub];
#pragma unroll
    for (int u = 0; u < 8; ++u) {
      float wn = __int_as_float(e[u].y);
      a0 = fmaf(wn, bf_lo(hv[u].x), a0);
      a1 = fmaf(wn, bf_hi(hv[u].x), a1);
      a2 = fmaf(wn, bf_lo(hv[u].y), a2);
      a3 = fmaf(wn, bf_hi(hv[u].y), a3);
    }
  }
  for (; j < end; ++j) {
    int2 e0 = epack[j];
    uint2 hu = h64[(size_t)e0.x * 16 + sub];
    float wn = __int_as_float(e0.y);
    a0 = fmaf(wn, bf_lo(hu.x), a0);
    a1 = fmaf(wn, bf_hi(hu.x), a1);
    a2 = fmaf(wn, bf_lo(hu.y), a2);
    a3 = fmaf(wn, bf_hi(hu.y), a3);
  }
  float4 v;
  if (RELU_NORM) {
    v.x = fmaxf(a0, 0.f); v.y = fmaxf(a1, 0.f);
    v.z = fmaxf(a2, 0.f); v.w = fmaxf(a3, 0.f);
    float ss = v.x * v.x + v.y * v.y + v.z * v.z + v.w * v.w;
#pragma unroll
    for (int off = 8; off; off >>= 1) ss += __shfl_xor(ss, off, 64);  // within 16-lane quarter
    float inv = 1.f / fmaxf(sqrtf(ss), 1e-12f);
    v.x *= inv; v.y *= inv; v.z *= inv; v.w *= inv;
  } else {
    v = make_float4(a0, a1, a2, a3);
  }
  *(float4*)&out[(size_t)node * HID + sub * 4] = v;
}

// ---------- atomic fallback path (fp32; only if ws too small for CSR) ----------

__global__ void init_agg_kernel(const float* __restrict__ dinv, const float* __restrict__ h,
                                const float* __restrict__ bias, float* __restrict__ out, int N) {
  int t = blockIdx.x * blockDim.x + threadIdx.x;
  int i = t >> 6, f = t & 63;
  if (i >= N) return;
  float di = dinv[i];
  out[t] = di * di * h[t] + bias[f];
}

__global__ void edge_atomic_kernel(const int* __restrict__ src, const int* __restrict__ dst,
                                   const float* __restrict__ dinv, const float* __restrict__ h,
                                   float* __restrict__ out, int E) {
  int t = blockIdx.x * blockDim.x + threadIdx.x;
  int e = t >> 6;
  if (e >= E) return;
  int f = t & 63;
  int s = src[e], d = dst[e];
  atomicAdd(&out[(size_t)d * HID + f], dinv[s] * dinv[d] * h[(size_t)s * HID + f]);
}

__global__ void relu_norm_kernel(float* __restrict__ hbuf, int N) {
  int t = blockIdx.x * blockDim.x + threadIdx.x;
  int i = t >> 6;
  if (i >= N) return;
  float v = fmaxf(hbuf[t], 0.f);
  float ss = v * v;
#pragma unroll
  for (int off = 32; off; off >>= 1) ss += __shfl_xor(ss, off, 64);
  hbuf[t] = v / fmaxf(sqrtf(ss), 1e-12f);
}

// ---------- host ----------

extern "C" void kernel_launch(void* const* d_in, const int* in_sizes, int n_in,
                              void* d_out, int out_size, void* d_ws, size_t ws_size,
                              hipStream_t stream) {
  const float* x  = (const float*)d_in[0];
  const int*   ei = (const int*)d_in[1];
  const float* W1 = (const float*)d_in[2];
  const float* b1 = (const float*)d_in[3];
  const float* W2 = (const float*)d_in[4];
  const float* b2 = (const float*)d_in[5];
  const float* W3 = (const float*)d_in[6];
  const float* b3 = (const float*)d_in[7];
  float* out = (float*)d_out;

  const int IN = in_sizes[2] / HID;   // 256
  const int N  = in_sizes[0] / IN;    // 100000
  const int E  = in_sizes[1] / 2;     // 1600000
  const int* srcI = ei;
  const int* dstI = ei + E;

  char* w = (char*)d_ws;
  size_t off = 0;
  auto alloc = [&](size_t bytes) { void* p = w + off; off = align256(off + bytes); return p; };
  float* A      = (float*)alloc((size_t)N * HID * 4);  // fp32 fallback / bf16 gather buffer
  float* dinv   = (float*)alloc((size_t)N * 4);
  int*   cnt    = (int*)alloc((size_t)N * 4);
  size_t base_need = off;
  int*   rowptr = (int*)alloc((size_t)(N + 1) * 4);
  int*   cursor = (int*)alloc((size_t)N * 4);
  int*   bsum   = (int*)alloc(1024 * 4);
  int*   boff   = (int*)alloc(1024 * 4);
  int2*  epack  = (int2*)alloc((size_t)E * 8);
  size_t csr_need = off;

  if (base_need > ws_size) return;
  const bool use_csr = (csr_need <= ws_size);
  __hip_bfloat16* Ab = (__hip_bfloat16*)A;
  uint2* Ab64 = (uint2*)A;

  const int blkE    = (E + 255) / 256;
  const int blkN    = (N + 255) / 256;
  const int blkScan = (N + 1023) / 1024;
  const int blkRow  = (N + 63) / 64;
  const int blkWave = (N * 64 + 255) / 256;
  const int blkAgg  = ((size_t)((N + 3) / 4) * 64 + 255) / 256;  // 4 nodes/wave
  const int blkEF   = ((size_t)E * 64 + 255) / 256;

  hipMemsetAsync(cnt, 0, (size_t)N * 4, stream);
  count_dst_kernel<<<blkE, 256, 0, stream>>>(dstI, cnt, E);
  dinv_kernel<<<blkN, 256, 0, stream>>>(cnt, dinv, N);

  if (use_csr) {
    scan_local_kernel<<<blkScan, 1024, 0, stream>>>(cnt, rowptr, bsum, N);
    scan_bsum_kernel<<<1, 1024, 0, stream>>>(bsum, boff, rowptr + N, blkScan);
    scan_add_kernel<<<blkN, 256, 0, stream>>>(boff, rowptr, cursor, N);
    scatter_kernel<<<blkE, 256, 0, stream>>>(srcI, dstI, dinv, cursor, epack, E);

    gemm_kernel<256><<<blkRow, 256, 0, stream>>>(x, W1, Ab, N);
    agg_kernel<true><<<blkAgg, 256, 0, stream>>>(rowptr, epack, dinv, Ab64, b1, out, N);
    gemm_kernel<64><<<blkRow, 256, 0, stream>>>(out, W2, Ab, N);
    agg_kernel<true><<<blkAgg, 256, 0, stream>>>(rowptr, epack, dinv, Ab64, b2, out, N);
    gemm_kernel<64><<<blkRow, 256, 0, stream>>>(out, W3, Ab, N);
    agg_kernel<false><<<blkAgg, 256, 0, stream>>>(rowptr, epack, dinv, Ab64, b3, out, N);
  } else {
    gemm_kernel<256><<<blkRow, 256, 0, stream>>>(x, W1, A, N);
    init_agg_kernel<<<blkWave, 256, 0, stream>>>(dinv, A, b1, out, N);
    edge_atomic_kernel<<<blkEF, 256, 0, stream>>>(srcI, dstI, dinv, A, out, E);
    relu_norm_kernel<<<blkWave, 256, 0, stream>>>(out, N);

    gemm_kernel<64><<<blkRow, 256, 0, stream>>>(out, W2, A, N);
    init_agg_kernel<<<blkWave, 256, 0, stream>>>(dinv, A, b2, out, N);
    edge_atomic_kernel<<<blkEF, 256, 0, stream>>>(srcI, dstI, dinv, A, out, E);
    relu_norm_kernel<<<blkWave, 256, 0, stream>>>(out, N);

    gemm_kernel<64><<<blkRow, 256, 0, stream>>>(out, W3, A, N);
    init_agg_kernel<<<blkWave, 256, 0, stream>>>(dinv, A, b3, out, N);
    edge_atomic_kernel<<<blkEF, 256, 0, stream>>>(srcI, dstI, dinv, A, out, E);
  }
}